// Round 3
// baseline (862.790 us; speedup 1.0000x reference)
//
#include <hip/hip_runtime.h>
#include <hip/hip_bf16.h>

// LGCN_Encoder, bf16-split MFMA, pre-split V, LDS-free reduce+expand.
// per layer: projT = ego^T V ; ego = V @ (diag(f_k) proj) ; out += ego ; /4 at end.
// MFMA 16x16x32_bf16 layouts (HW-verified m89/m91):
//   A[m=lane&15][k=(lane>>4)*8+j], B[k=(lane>>4)*8+j][n=lane&15],
//   C[row=(lane>>4)*4+reg][col=lane&15].

#define N_USERS 29858
#define N_TOTAL 70839
#define DQ 64
#define FD 512
#define N_LAYERS 3
#define NPAD 71168   // 139*512: multiple of 512 (reduce K-chunks) and 64 (expand blocks)

typedef __attribute__((ext_vector_type(8))) short short8;
typedef __attribute__((ext_vector_type(4))) short short4v;
typedef __attribute__((ext_vector_type(4))) float f32x4;

static __device__ __forceinline__ unsigned short bf16_rne(float x) {
  union { float f; unsigned u; } a; a.f = x;
  return (unsigned short)((a.u + 0x7FFFu + ((a.u >> 16) & 1u)) >> 16);
}
static __device__ __forceinline__ float bf16_f(unsigned short h) {
  union { unsigned u; float f; } a; a.u = ((unsigned)h) << 16;
  return a.f;
}
static __device__ __forceinline__ void split2(float x, unsigned short& h, unsigned short& l) {
  h = bf16_rne(x);
  l = bf16_rne(x - bf16_f(h));
}

// ---------------------------------------------------------------- split_v
// Vh/Vl[n][f] = split(v[n][f]); rows [N_TOTAL, NPAD) zero-filled.
__global__ __launch_bounds__(256) void split_v_kernel(
    const float* __restrict__ v, unsigned short* __restrict__ vh,
    unsigned short* __restrict__ vl) {
  size_t g = (size_t)blockIdx.x * 256 + threadIdx.x;  // one 8-float group
  size_t base = g * 8;
  int n = (int)(base >> 9);  // FD=512
  short8 hv = {0, 0, 0, 0, 0, 0, 0, 0};
  short8 lv = {0, 0, 0, 0, 0, 0, 0, 0};
  if (n < N_TOTAL) {
    f32x4 a = *(const f32x4*)(v + base);
    f32x4 b = *(const f32x4*)(v + base + 4);
#pragma unroll
    for (int j = 0; j < 8; ++j) {
      float x = (j < 4) ? a[j] : b[j - 4];
      unsigned short h, l;
      split2(x, h, l);
      hv[j] = (short)h; lv[j] = (short)l;
    }
  }
  *(short8*)(vh + base) = hv;
  *(short8*)(vl + base) = lv;
}

// ---------------------------------------------------------------- init
// out = concat(user,item); egoT_h/l[d][n] = split(ego0[n][d]); zero-pad n>=N_TOTAL.
__global__ __launch_bounds__(256) void init_kernel(
    const float* __restrict__ u, const float* __restrict__ it,
    float* __restrict__ out, unsigned short* __restrict__ egoT_h,
    unsigned short* __restrict__ egoT_l) {
  const int n0 = blockIdx.x * 64;
  const int t = threadIdx.x;
  const int nq = t & 15, dq = t >> 4;  // 4 n x 4 d per thread
  f32x4 rows[4];
#pragma unroll
  for (int r = 0; r < 4; ++r) {
    int n = n0 + nq * 4 + r;
    f32x4 val = {0.f, 0.f, 0.f, 0.f};
    if (n < N_TOTAL) {
      const float* src = (n < N_USERS) ? (u + (size_t)n * DQ)
                                       : (it + (size_t)(n - N_USERS) * DQ);
      val = *(const f32x4*)(src + dq * 4);
      *(f32x4*)(out + (size_t)n * DQ + dq * 4) = val;
    }
    rows[r] = val;
  }
#pragma unroll
  for (int i = 0; i < 4; ++i) {
    int d = dq * 4 + i;
    short4v hv, lv;
#pragma unroll
    for (int r = 0; r < 4; ++r) {
      unsigned short h, l;
      split2(rows[r][i], h, l);
      hv[r] = (short)h; lv[r] = (short)l;
    }
    *(short4v*)(egoT_h + (size_t)d * NPAD + n0 + nq * 4) = hv;
    *(short4v*)(egoT_l + (size_t)d * NPAD + n0 + nq * 4) = lv;
  }
}

// ---------------------------------------------------------------- reduce
// projT[d][f] += sum_n egoT[d][n] * V[n][f] over this block's 512-row K-chunk.
// A = egoT (contiguous 16B), B = Vh/Vl via 8 u16 gathers (line-efficient).
// grid (8 f-slices, 139 K-chunks); wave owns one 16-f tile x all 64 d.
__global__ __launch_bounds__(256, 6) void reduce_kernel(
    const unsigned short* __restrict__ vh, const unsigned short* __restrict__ vl,
    const unsigned short* __restrict__ egoT_h,
    const unsigned short* __restrict__ egoT_l, float* __restrict__ projT) {
  const int t = threadIdx.x;
  const int lane = t & 63, wv = t >> 6;
  const int m16 = lane & 15, quad = lane >> 4;
  const int fbw = blockIdx.x * 64 + wv * 16;
  const int n0 = blockIdx.y * 512;

  f32x4 acc[4];
#pragma unroll
  for (int i = 0; i < 4; ++i) acc[i] = (f32x4){0.f, 0.f, 0.f, 0.f};

  const unsigned short* bph = vh + (size_t)(n0 + quad * 8) * FD + fbw + m16;
  const unsigned short* bpl = vl + (size_t)(n0 + quad * 8) * FD + fbw + m16;
  const unsigned short* aph = egoT_h + (size_t)m16 * NPAD + n0 + quad * 8;
  const unsigned short* apl = egoT_l + (size_t)m16 * NPAD + n0 + quad * 8;

#pragma unroll 2
  for (int s = 0; s < 16; ++s) {
    short8 bh, bl;
#pragma unroll
    for (int j = 0; j < 8; ++j) {
      bh[j] = (short)bph[(size_t)j * FD];
      bl[j] = (short)bpl[(size_t)j * FD];
    }
#pragma unroll
    for (int mt = 0; mt < 4; ++mt) {
      short8 ah = *(const short8*)(aph + (size_t)mt * 16 * NPAD);
      short8 al = *(const short8*)(apl + (size_t)mt * 16 * NPAD);
      acc[mt] = __builtin_amdgcn_mfma_f32_16x16x32_bf16(ah, bh, acc[mt], 0, 0, 0);
      acc[mt] = __builtin_amdgcn_mfma_f32_16x16x32_bf16(ah, bl, acc[mt], 0, 0, 0);
      acc[mt] = __builtin_amdgcn_mfma_f32_16x16x32_bf16(al, bh, acc[mt], 0, 0, 0);
    }
    bph += 32 * FD; bpl += 32 * FD;
    aph += 32; apl += 32;
  }
  // C: projT[d = mt*16 + quad*4 + reg][f = fbw + m16]
#pragma unroll
  for (int mt = 0; mt < 4; ++mt)
#pragma unroll
    for (int reg = 0; reg < 4; ++reg)
      atomicAdd(&projT[(mt * 16 + quad * 4 + reg) * FD + fbw + m16],
                acc[mt][reg]);
}

// ---------------------------------------------------------------- prep_w
// Wt[d][f] = split(filt[f] * projT[d][f])  (bf16 h/l, [64][512])
__global__ __launch_bounds__(256) void prep_w(
    const float* __restrict__ projT, const float* __restrict__ filt,
    unsigned short* __restrict__ wt_h, unsigned short* __restrict__ wt_l) {
  int idx = blockIdx.x * 256 + threadIdx.x;  // 4096 threads
  int d = idx >> 6;
  int f8 = (idx & 63) * 8;
  short8 hv, lv;
#pragma unroll
  for (int j = 0; j < 8; ++j) {
    int f = f8 + j;
    float w = filt[f] * projT[d * FD + f];
    unsigned short h, l;
    split2(w, h, l);
    hv[j] = (short)h; lv[j] = (short)l;
  }
  *(short8*)(wt_h + d * FD + f8) = hv;
  *(short8*)(wt_l + d * FD + f8) = lv;
}

// ---------------------------------------------------------------- expand
// ego_new[n][d] = sum_f V[n][f] * Wt[d][f]; out=(out+ego_new)*scale; egoT updated.
// Wave owns 16 n-rows x 64 d; all fragment loads contiguous 16B. grid NPAD/64.
__global__ __launch_bounds__(256, 6) void expand_kernel(
    const unsigned short* __restrict__ vh, const unsigned short* __restrict__ vl,
    const unsigned short* __restrict__ wt_h, const unsigned short* __restrict__ wt_l,
    float* __restrict__ out, unsigned short* __restrict__ egoT_h,
    unsigned short* __restrict__ egoT_l, float scale, int write_ego) {
  const int t = threadIdx.x;
  const int lane = t & 63, wv = t >> 6;
  const int m16 = lane & 15, quad = lane >> 4;
  const int nbw = blockIdx.x * 64 + wv * 16;

  const unsigned short* aph = vh + (size_t)(nbw + m16) * FD + quad * 8;
  const unsigned short* apl = vl + (size_t)(nbw + m16) * FD + quad * 8;
  const unsigned short* wph = wt_h + (size_t)m16 * FD + quad * 8;
  const unsigned short* wpl = wt_l + (size_t)m16 * FD + quad * 8;

  f32x4 acc[4];
#pragma unroll
  for (int i = 0; i < 4; ++i) acc[i] = (f32x4){0.f, 0.f, 0.f, 0.f};

#pragma unroll 2
  for (int s = 0; s < 16; ++s) {
    short8 ah = *(const short8*)(aph);
    short8 al = *(const short8*)(apl);
#pragma unroll
    for (int dt = 0; dt < 4; ++dt) {
      short8 bh = *(const short8*)(wph + (size_t)dt * 16 * FD);
      short8 bl = *(const short8*)(wpl + (size_t)dt * 16 * FD);
      acc[dt] = __builtin_amdgcn_mfma_f32_16x16x32_bf16(ah, bh, acc[dt], 0, 0, 0);
      acc[dt] = __builtin_amdgcn_mfma_f32_16x16x32_bf16(ah, bl, acc[dt], 0, 0, 0);
      acc[dt] = __builtin_amdgcn_mfma_f32_16x16x32_bf16(al, bh, acc[dt], 0, 0, 0);
    }
    aph += 32; apl += 32;
    wph += 32; wpl += 32;
  }

  // C: n = nbw + quad*4 + reg, d = dt*16 + m16
  const int nrow = nbw + quad * 4;
#pragma unroll
  for (int dt = 0; dt < 4; ++dt) {
    int d = dt * 16 + m16;
#pragma unroll
    for (int reg = 0; reg < 4; ++reg) {
      int n = nrow + reg;
      if (n < N_TOTAL) {
        float* op = out + (size_t)n * DQ + d;
        *op = (*op + acc[dt][reg]) * scale;
      }
    }
    if (write_ego) {
      short4v hv, lv;
#pragma unroll
      for (int reg = 0; reg < 4; ++reg) {
        unsigned short h = 0, l = 0;
        if (nrow + reg < N_TOTAL) split2(acc[dt][reg], h, l);
        hv[reg] = (short)h; lv[reg] = (short)l;
      }
      *(short4v*)(egoT_h + (size_t)d * NPAD + nrow) = hv;
      *(short4v*)(egoT_l + (size_t)d * NPAD + nrow) = lv;
    }
  }
}

// ---------------------------------------------------------------- launch
extern "C" void kernel_launch(void* const* d_in, const int* in_sizes, int n_in,
                              void* d_out, int out_size, void* d_ws, size_t ws_size,
                              hipStream_t stream) {
  const float* user_emb = (const float*)d_in[0];
  const float* item_emb = (const float*)d_in[1];
  const float* v        = (const float*)d_in[2];
  const float* filters  = (const float*)d_in[3];
  float* out = (float*)d_out;

  // workspace: Vh,Vl [NPAD*FD] u16; egoT h/l [DQ*NPAD] u16; projT [DQ*FD] f32; wt h/l
  unsigned short* vh     = (unsigned short*)d_ws;
  unsigned short* vl     = vh + (size_t)NPAD * FD;
  unsigned short* egoT_h = vl + (size_t)NPAD * FD;
  unsigned short* egoT_l = egoT_h + (size_t)DQ * NPAD;
  float* projT           = (float*)(egoT_l + (size_t)DQ * NPAD);
  unsigned short* wt_h   = (unsigned short*)(projT + (size_t)DQ * FD);
  unsigned short* wt_l   = wt_h + (size_t)DQ * FD;

  split_v_kernel<<<(NPAD / 64) * (FD / 32), 256, 0, stream>>>(v, vh, vl);  // 17792 blocks
  init_kernel<<<NPAD / 64, 256, 0, stream>>>(user_emb, item_emb, out, egoT_h, egoT_l);

  for (int k = 0; k < N_LAYERS; ++k) {
    hipMemsetAsync(projT, 0, (size_t)DQ * FD * sizeof(float), stream);
    reduce_kernel<<<dim3(8, NPAD / 512), 256, 0, stream>>>(vh, vl, egoT_h, egoT_l, projT);
    prep_w<<<16, 256, 0, stream>>>(projT, filters + (size_t)k * FD, wt_h, wt_l);
    float scale = (k == N_LAYERS - 1) ? (1.0f / (N_LAYERS + 1)) : 1.0f;
    expand_kernel<<<NPAD / 64, 256, 0, stream>>>(
        vh, vl, wt_h, wt_l, out, egoT_h, egoT_l, scale, (k < N_LAYERS - 1) ? 1 : 0);
  }
}

// Round 4
// 655.818 us; speedup vs baseline: 1.3156x; 1.3156x over previous
//
#include <hip/hip_runtime.h>
#include <hip/hip_bf16.h>

// LGCN_Encoder via Gram-matrix collapse.
//   G = V^T V (512x512, layer-invariant), c0 = V^T ego0
//   c_{k+1} = G (f_k ⊙ c_k)  [tiny]
//   out = (ego0 + V (w1+w2+w3))/4,  w_k = f_{k-1} ⊙ c_{k-1}
// V is streamed exactly twice (gram, expand). All big GEMMs use bf16
// trunc-split MFMA 16x16x32 (a*b ≈ ah*bh + ah*bl + al*bh, err ~2^-16).
// Layouts (HW-verified m89/m91): A[m=lane&15][k=quad*8+j],
// B[k=quad*8+j][col=lane&15], C[row=quad*4+reg][col=lane&15].

#define N_USERS 29858
#define N_TOTAL 70839
#define DQ 64
#define FD 512
#define NPAD 71168   // 139*512
#define NC 35        // gram split-K chunks (last ragged)
#define CHUNK 2048
#define NST 40       // VT row stride in u16 (16B aligned)

typedef __attribute__((ext_vector_type(8))) short short8;
typedef __attribute__((ext_vector_type(4))) short short4v;
typedef __attribute__((ext_vector_type(4))) float f32x4;
typedef unsigned int u32;
typedef unsigned short u16;

static __device__ __forceinline__ u32 f32u(float x){union{float f;u32 u;}a;a.f=x;return a.u;}
static __device__ __forceinline__ float uf32(u32 u){union{u32 u;float f;}a;a.u=u;return a.f;}
// pack high halves: (hi16(x1)<<16) | hi16(x0)
static __device__ __forceinline__ u32 pack_h(u32 x0, u32 x1){
  return __builtin_amdgcn_perm(x1, x0, 0x07060302u);
}
// exact trunc split of two f32 into bf16 h-pair and l-pair dwords
static __device__ __forceinline__ void split_pair(u32 x0, u32 x1, u32& hp, u32& lp) {
  hp = pack_h(x0, x1);
  u32 l0 = f32u(uf32(x0) - uf32(x0 & 0xFFFF0000u));
  u32 l1 = f32u(uf32(x1) - uf32(x1 & 0xFFFF0000u));
  lp = pack_h(l0, l1);
}
union U8x { u32 u[4]; short8 s; };

static __device__ __forceinline__ u16 bf16_rne(float x) {
  u32 u = f32u(x);
  return (u16)((u + 0x7FFFu + ((u >> 16) & 1u)) >> 16);
}
static __device__ __forceinline__ void split2(float x, u16& h, u16& l) {
  h = bf16_rne(x);
  l = bf16_rne(x - uf32(((u32)h) << 16));
}

static __device__ __forceinline__ void load_lds16(const float* g, float* l) {
  __builtin_amdgcn_global_load_lds(
      (const __attribute__((address_space(1))) u32*)(g),
      (__attribute__((address_space(3))) u32*)(l), 16, 0, 0);
}

// ---------------------------------------------------------------- init
// out = concat(user,item); egoT_h/l[d][n] = split(ego0[n][d]); zero-pad n>=N_TOTAL
__global__ __launch_bounds__(256) void init_kernel(
    const float* __restrict__ u, const float* __restrict__ it,
    float* __restrict__ out, u16* __restrict__ egoT_h, u16* __restrict__ egoT_l) {
  const int n0 = blockIdx.x * 64;
  const int t = threadIdx.x;
  const int nq = t & 15, dq = t >> 4;
  f32x4 rows[4];
#pragma unroll
  for (int r = 0; r < 4; ++r) {
    int n = n0 + nq * 4 + r;
    f32x4 val = {0.f, 0.f, 0.f, 0.f};
    if (n < N_TOTAL) {
      const float* src = (n < N_USERS) ? (u + (size_t)n * DQ)
                                       : (it + (size_t)(n - N_USERS) * DQ);
      val = *(const f32x4*)(src + dq * 4);
      *(f32x4*)(out + (size_t)n * DQ + dq * 4) = val;
    }
    rows[r] = val;
  }
#pragma unroll
  for (int i = 0; i < 4; ++i) {
    int d = dq * 4 + i;
    short4v hv, lv;
#pragma unroll
    for (int r = 0; r < 4; ++r) {
      u16 h, l;
      split2(rows[r][i], h, l);
      hv[r] = (short)h; lv[r] = (short)l;
    }
    *(short4v*)(egoT_h + (size_t)d * NPAD + n0 + nq * 4) = hv;
    *(short4v*)(egoT_l + (size_t)d * NPAD + n0 + nq * 4) = lv;
  }
}

// ---------------------------------------------------------------- gram
// 14 jobs: 0..11 G-tiles (256 rows x 64 cols, upper-incl), 12..13 c0-tiles.
// Per chunk: stage transposed bf16-split V-slice in LDS; 3-MFMA accumulate;
// write partials (no atomics). parts[NC][512][576] (576 = 512 G-cols + 64 c0).
__global__ __launch_bounds__(256) void gram_kernel(
    const float* __restrict__ v, const u16* __restrict__ egoT_h,
    const u16* __restrict__ egoT_l, float* __restrict__ parts) {
  __shared__ u16 VAh[256 * NST];
  __shared__ u16 VAl[256 * NST];
  __shared__ u16 VBh[64 * NST];
  __shared__ u16 VBl[64 * NST];

  const int job = blockIdx.x;
  const int n0c = blockIdx.y * CHUNK;
  const int nend = min(n0c + CHUNK, NPAD);
  const bool isC0 = (job >= 12);
  const int itile = isC0 ? (job - 12) : (job < 8 ? 0 : 1);
  const int fA = itile * 256;
  const int jcol = isC0 ? 0 : (job < 8 ? job : job - 4);
  const int colbase = jcol * 64;
  const bool reuseB = !isC0 && (colbase >= fA) && (colbase + 64 <= fA + 256);
  const bool stageB = !isC0 && !reuseB;

  const int t = threadIdx.x;
  const int lane = t & 63, wv = t >> 6;
  const int m16 = lane & 15, quad = lane >> 4;
  const int fl = t & 63, nq = t >> 6;

  f32x4 acc[4][4];
#pragma unroll
  for (int a = 0; a < 4; ++a)
#pragma unroll
    for (int b = 0; b < 4; ++b) acc[a][b] = (f32x4){0.f, 0.f, 0.f, 0.f};

  for (int n0 = n0c; n0 < nend; n0 += 32) {
    __syncthreads();
    // stage A-slice: 32 n x 256 f, transposed split into VAh/VAl
#pragma unroll
    for (int seg = 0; seg < 4; ++seg) {
      u32 xu[8];
#pragma unroll
      for (int r = 0; r < 8; ++r) {
        int n = n0 + nq * 8 + r;
        float x = (n < N_TOTAL) ? v[(size_t)n * FD + fA + seg * 64 + fl] : 0.f;
        xu[r] = f32u(x);
      }
      int frow = seg * 64 + fl;
#pragma unroll
      for (int p = 0; p < 4; ++p) {
        u32 hp, lp;
        split_pair(xu[2 * p], xu[2 * p + 1], hp, lp);
        *(u32*)(VAh + frow * NST + nq * 8 + 2 * p) = hp;
        *(u32*)(VAl + frow * NST + nq * 8 + 2 * p) = lp;
      }
    }
    if (stageB) {  // 32 n x 64 f
      u32 xu[8];
#pragma unroll
      for (int r = 0; r < 8; ++r) {
        int n = n0 + nq * 8 + r;
        float x = (n < N_TOTAL) ? v[(size_t)n * FD + colbase + fl] : 0.f;
        xu[r] = f32u(x);
      }
#pragma unroll
      for (int p = 0; p < 4; ++p) {
        u32 hp, lp;
        split_pair(xu[2 * p], xu[2 * p + 1], hp, lp);
        *(u32*)(VBh + fl * NST + nq * 8 + 2 * p) = hp;
        *(u32*)(VBl + fl * NST + nq * 8 + 2 * p) = lp;
      }
    }
    __syncthreads();

    short8 ah[4], al[4];
#pragma unroll
    for (int mt = 0; mt < 4; ++mt) {
      int frow = wv * 64 + mt * 16 + m16;
      ah[mt] = *(const short8*)(VAh + frow * NST + quad * 8);
      al[mt] = *(const short8*)(VAl + frow * NST + quad * 8);
    }
    const u16* sbh = reuseB ? (VAh + (colbase - fA) * NST) : VBh;
    const u16* sbl = reuseB ? (VAl + (colbase - fA) * NST) : VBl;
#pragma unroll
    for (int ct = 0; ct < 4; ++ct) {
      short8 bh, bl;
      if (isC0) {
        bh = *(const short8*)(egoT_h + (size_t)(ct * 16 + m16) * NPAD + n0 + quad * 8);
        bl = *(const short8*)(egoT_l + (size_t)(ct * 16 + m16) * NPAD + n0 + quad * 8);
      } else {
        bh = *(const short8*)(sbh + (ct * 16 + m16) * NST + quad * 8);
        bl = *(const short8*)(sbl + (ct * 16 + m16) * NST + quad * 8);
      }
#pragma unroll
      for (int mt = 0; mt < 4; ++mt) {
        acc[mt][ct] = __builtin_amdgcn_mfma_f32_16x16x32_bf16(ah[mt], bh, acc[mt][ct], 0, 0, 0);
        acc[mt][ct] = __builtin_amdgcn_mfma_f32_16x16x32_bf16(ah[mt], bl, acc[mt][ct], 0, 0, 0);
        acc[mt][ct] = __builtin_amdgcn_mfma_f32_16x16x32_bf16(al[mt], bh, acc[mt][ct], 0, 0, 0);
      }
    }
  }

  float* pb = parts + (size_t)blockIdx.y * (512 * 576);
  const int cb = isC0 ? 512 : colbase;
#pragma unroll
  for (int mt = 0; mt < 4; ++mt) {
    int row = fA + wv * 64 + mt * 16 + quad * 4;
#pragma unroll
    for (int ct = 0; ct < 4; ++ct) {
      int col = cb + ct * 16 + m16;
#pragma unroll
      for (int reg = 0; reg < 4; ++reg)
        pb[(size_t)(row + reg) * 576 + col] = acc[mt][ct][reg];
    }
  }
}

// ---------------------------------------------------------------- finalize
// Sum partials; mirror lower triangle of G; emit G [512][512] and c0 [512][64].
__global__ __launch_bounds__(256) void finalize_kernel(
    const float* __restrict__ parts, float* __restrict__ G, float* __restrict__ c0) {
  int idx = blockIdx.x * 256 + threadIdx.x;  // 512*576
  int r = idx / 576, c = idx % 576;
  float s = 0.f;
  if (c >= 512) {
    for (int p = 0; p < NC; ++p) s += parts[(size_t)p * (512 * 576) + r * 576 + c];
    c0[r * 64 + (c - 512)] = s;
  } else {
    bool direct = (c >> 6) >= 4 * (r >> 8);
    int rr = direct ? r : c, cc = direct ? c : r;
    for (int p = 0; p < NC; ++p) s += parts[(size_t)p * (512 * 576) + rr * 576 + cc];
    G[r * 512 + c] = s;
  }
}

// ---------------------------------------------------------------- apply_g
// cout = G @ (filt ⊙ cin), fp32 VALU. grid 128 x 256.
__global__ __launch_bounds__(256) void apply_g_kernel(
    const float* __restrict__ G, const float* __restrict__ filt,
    const float* __restrict__ cin, float* __restrict__ cout) {
  int i = blockIdx.x * 4 + (threadIdx.x >> 6);
  int d = threadIdx.x & 63;
  float s = 0.f;
#pragma unroll 8
  for (int j = 0; j < 512; ++j)
    s += G[i * 512 + j] * (filt[j] * cin[j * 64 + d]);
  cout[i * 64 + d] = s;
}

// ---------------------------------------------------------------- prep_wt
// wsum = f0⊙c0 + f1⊙c1 + f2⊙c2; wt_h/l[d][f] = split(wsum[f][d])
__global__ __launch_bounds__(256) void prep_wt_kernel(
    const float* __restrict__ filters, const float* __restrict__ c0,
    const float* __restrict__ c1, const float* __restrict__ c2,
    u16* __restrict__ wt_h, u16* __restrict__ wt_l) {
  int idx = blockIdx.x * 256 + threadIdx.x;  // 64*512
  int d = idx >> 9, f = idx & 511;
  float w = filters[f] * c0[f * 64 + d] + filters[512 + f] * c1[f * 64 + d] +
            filters[1024 + f] * c2[f * 64 + d];
  u32 xu = f32u(w);
  u32 h = xu & 0xFFFF0000u;
  u32 lu = f32u(w - uf32(h));
  wt_h[d * FD + f] = (u16)(xu >> 16);
  wt_l[d * FD + f] = (u16)(lu >> 16);
}

// ---------------------------------------------------------------- expand
// out = (out + V @ wsum) * 0.25. A staged via global_load_lds (fp32, split in reg).
__global__ __launch_bounds__(256) void expand_kernel(
    const float* __restrict__ v, const u16* __restrict__ wt_h,
    const u16* __restrict__ wt_l, float* __restrict__ out) {
  __shared__ float raw[128 * 64];
  const int t = threadIdx.x;
  const int lane = t & 63, wv = t >> 6;
  const int m16 = lane & 15, quad = lane >> 4;
  const int nb = blockIdx.x * 128;

  f32x4 acc[2][4];
#pragma unroll
  for (int a = 0; a < 2; ++a)
#pragma unroll
    for (int b = 0; b < 4; ++b) acc[a][b] = (f32x4){0.f, 0.f, 0.f, 0.f};

  for (int fs = 0; fs < FD; fs += 64) {
    __syncthreads();
    // wave wv stages rows [wv*32, wv*32+32): 8 x 1KB direct-to-LDS
#pragma unroll
    for (int g = 0; g < 8; ++g) {
      int rloc = wv * 32 + g * 4 + (lane >> 4);
      int grow = min(nb + rloc, N_TOTAL - 1);  // clamp: padded rows discarded later
      const float* gp = v + (size_t)grow * FD + fs + (lane & 15) * 4;
      load_lds16(gp, raw + (wv * 32 + g * 4) * 64);
    }
    __syncthreads();
#pragma unroll
    for (int k0 = 0; k0 < 64; k0 += 32) {
      short8 ah[2], al[2];
#pragma unroll
      for (int mt = 0; mt < 2; ++mt) {
        const float* rp = raw + (wv * 32 + mt * 16 + m16) * 64 + k0 + quad * 8;
        f32x4 xa = *(const f32x4*)rp;
        f32x4 xb = *(const f32x4*)(rp + 4);
        U8x H, L;
        split_pair(f32u(xa[0]), f32u(xa[1]), H.u[0], L.u[0]);
        split_pair(f32u(xa[2]), f32u(xa[3]), H.u[1], L.u[1]);
        split_pair(f32u(xb[0]), f32u(xb[1]), H.u[2], L.u[2]);
        split_pair(f32u(xb[2]), f32u(xb[3]), H.u[3], L.u[3]);
        ah[mt] = H.s; al[mt] = L.s;
      }
#pragma unroll
      for (int ct = 0; ct < 4; ++ct) {
        short8 bh = *(const short8*)(wt_h + (size_t)(ct * 16 + m16) * FD + fs + k0 + quad * 8);
        short8 bl = *(const short8*)(wt_l + (size_t)(ct * 16 + m16) * FD + fs + k0 + quad * 8);
#pragma unroll
        for (int mt = 0; mt < 2; ++mt) {
          acc[mt][ct] = __builtin_amdgcn_mfma_f32_16x16x32_bf16(ah[mt], bh, acc[mt][ct], 0, 0, 0);
          acc[mt][ct] = __builtin_amdgcn_mfma_f32_16x16x32_bf16(ah[mt], bl, acc[mt][ct], 0, 0, 0);
          acc[mt][ct] = __builtin_amdgcn_mfma_f32_16x16x32_bf16(al[mt], bh, acc[mt][ct], 0, 0, 0);
        }
      }
    }
  }

#pragma unroll
  for (int mt = 0; mt < 2; ++mt) {
    int nrow = nb + wv * 32 + mt * 16 + quad * 4;
#pragma unroll
    for (int ct = 0; ct < 4; ++ct) {
      int d = ct * 16 + m16;
#pragma unroll
      for (int reg = 0; reg < 4; ++reg) {
        int n = nrow + reg;
        if (n < N_TOTAL) {
          float* op = out + (size_t)n * DQ + d;
          *op = (*op + acc[mt][ct][reg]) * 0.25f;
        }
      }
    }
  }
}

// ---------------------------------------------------------------- launch
extern "C" void kernel_launch(void* const* d_in, const int* in_sizes, int n_in,
                              void* d_out, int out_size, void* d_ws, size_t ws_size,
                              hipStream_t stream) {
  const float* user_emb = (const float*)d_in[0];
  const float* item_emb = (const float*)d_in[1];
  const float* v        = (const float*)d_in[2];
  const float* filters  = (const float*)d_in[3];
  float* out = (float*)d_out;

  u16* egoT_h = (u16*)d_ws;                                   // 64*NPAD
  u16* egoT_l = egoT_h + (size_t)DQ * NPAD;                   // 64*NPAD
  float* parts = (float*)(egoT_l + (size_t)DQ * NPAD);        // NC*512*576
  float* G     = parts + (size_t)NC * 512 * 576;              // 512*512
  float* c0    = G + 512 * 512;                               // 512*64
  float* c1    = c0 + 512 * 64;
  float* c2    = c1 + 512 * 64;
  u16* wt_h    = (u16*)(c2 + 512 * 64);                       // 64*512
  u16* wt_l    = wt_h + (size_t)DQ * FD;

  init_kernel<<<NPAD / 64, 256, 0, stream>>>(user_emb, item_emb, out, egoT_h, egoT_l);
  gram_kernel<<<dim3(14, NC), 256, 0, stream>>>(v, egoT_h, egoT_l, parts);
  finalize_kernel<<<(512 * 576) / 256, 256, 0, stream>>>(parts, G, c0);
  apply_g_kernel<<<128, 256, 0, stream>>>(G, filters, c0, c1);
  apply_g_kernel<<<128, 256, 0, stream>>>(G, filters + 512, c1, c2);
  prep_wt_kernel<<<128, 256, 0, stream>>>(filters, c0, c1, c2, wt_h, wt_l);
  expand_kernel<<<NPAD / 128, 256, 0, stream>>>(v, wt_h, wt_l, out);
}